// Round 6
// baseline (589.549 us; speedup 1.0000x reference)
//
#include <hip/hip_runtime.h>
#include <hip/hip_bf16.h>

// Qwen2 attention layer: S=2048, HIDDEN=3584, 28 Q heads, 4 KV heads, D=128.
// fp32 inputs auto-detected -> bf16 pipeline (MFMA), fp32 output.
// R6: GEMM K-loop restructured hipBLASLt-style: triple-buffered LDS, prefetch
// depth 2, raw s_barrier + s_waitcnt vmcnt(4) (never 0) so one full stage
// stays in flight across every barrier. Split-K + reduce passes dropped.

#define S_LEN 2048
#define HID   3584
#define NH    28
#define NKV   4
#define HD    128
#define GQA   7

using bf16x8 = __attribute__((ext_vector_type(8))) __bf16;
using f32x4  = __attribute__((ext_vector_type(4))) float;

#define LOG2E 1.4426950408889634f
#define SM_SCALE 0.08838834764831845f  // 1/sqrt(128)

// gfx9 s_waitcnt encoding: vmcnt[3:0] | expcnt<<4 | lgkmcnt<<8 | vmcnt[5:4]<<14
#define WAIT_VM4 0x0F74   // vmcnt<=4, lgkm/exp don't-care
#define WAIT_VM0 0x0F70   // vmcnt<=0

__device__ __forceinline__ float b2f(unsigned short u) {
    unsigned int x = ((unsigned int)u) << 16;
    float f;
    __builtin_memcpy(&f, &x, 4);
    return f;
}

__device__ __forceinline__ unsigned short f2b(float f) {
    unsigned int i;
    __builtin_memcpy(&i, &f, 4);
    i += 0x7FFFu + ((i >> 16) & 1u);  // RNE
    return (unsigned short)(i >> 16);
}

__device__ __forceinline__ void gload16(const void* g, void* l) {
    __builtin_amdgcn_global_load_lds(
        (__attribute__((address_space(1))) void*)(g),
        (__attribute__((address_space(3))) void*)(l), 16, 0, 0);
}

// ---------- dtype detection ----------
__global__ __launch_bounds__(256) void detect_kernel(
    const unsigned short* __restrict__ X, int* __restrict__ flag)
{
    __shared__ int sflag;
    if (threadIdx.x == 0) sflag = 0;
    __syncthreads();
    bool insane = false;
    for (int i = threadIdx.x; i < 8192; i += 256) {
        unsigned int e = (X[i] >> 7) & 0xFF;
        if (e >= 0xE0) insane = true;
    }
    if (insane) sflag = 1;  // benign race
    __syncthreads();
    if (threadIdx.x == 0) flag[0] = sflag;
}

// ---------- fused convert: all 8 tensors -> one contiguous bf16 region ----------
#define SEG_B1 7340032L
#define SEG_B2 20185088L
#define SEG_B3 22020096L
#define SEG_B4 23855104L
#define SEG_B5 36700160L
#define SEG_B6 36703744L
#define SEG_B7 36704256L
#define SEG_B8 36704768L

__global__ __launch_bounds__(256) void convert_all(
    const void* __restrict__ s0, const void* __restrict__ s1,
    const void* __restrict__ s2, const void* __restrict__ s3,
    const void* __restrict__ s4, const void* __restrict__ s5,
    const void* __restrict__ s6, const void* __restrict__ s7,
    unsigned short* __restrict__ dst, const int* __restrict__ flag)
{
    const long i0 = ((long)blockIdx.x * 256 + threadIdx.x) * 8;
    if (i0 >= SEG_B8) return;
    const void* src;
    long off;
    if      (i0 < SEG_B1) { src = s0; off = i0; }
    else if (i0 < SEG_B2) { src = s1; off = i0 - SEG_B1; }
    else if (i0 < SEG_B3) { src = s2; off = i0 - SEG_B2; }
    else if (i0 < SEG_B4) { src = s3; off = i0 - SEG_B3; }
    else if (i0 < SEG_B5) { src = s4; off = i0 - SEG_B4; }
    else if (i0 < SEG_B6) { src = s5; off = i0 - SEG_B5; }
    else if (i0 < SEG_B7) { src = s6; off = i0 - SEG_B6; }
    else                  { src = s7; off = i0 - SEG_B7; }
    if (flag[0] != 0) {
        const float* s = (const float*)src + off;
        unsigned short o[8];
#pragma unroll
        for (int j = 0; j < 8; ++j) o[j] = f2b(s[j]);
        *(uint4*)(dst + i0) = *(const uint4*)o;
    } else {
        *(uint4*)(dst + i0) = *(const uint4*)((const unsigned short*)src + off);
    }
}

// ---------- pipelined GEMM core: C[M,N] = A[M,K] * B[N,K]^T (+bias) ----------
// 128x128 tile, BK=32, 256 threads, triple-buffered LDS, prefetch depth 2,
// raw s_barrier + s_waitcnt vmcnt(4): the newest stage stays in flight across
// the barrier (hipBLASLt-style), hiding ~900cyc HBM latency under 2 iters.
__device__ __forceinline__ void gemm_pipe(
    const unsigned short* __restrict__ A,
    const unsigned short* __restrict__ B,
    const unsigned short* __restrict__ bias,
    void* __restrict__ Cout,
    int K, int ldc, int m0, int n0,
    bool trans, bool hasBias, bool outF32,
    unsigned short* As, unsigned short* Bs)   // each 3*128*32 shorts
{
    const int tid  = threadIdx.x;
    const int w    = tid >> 6;
    const int l    = tid & 63;
    const int quad = l >> 4;
    const int t    = l & 15;
    const int wm   = w >> 1;
    const int wn   = w & 1;

    const unsigned short* aG0 = A + (unsigned long)(m0 + w * 32 + (l >> 2)) * K + ((l & 3) << 3);
    const unsigned short* aG1 = aG0 + 16ul * K;
    const unsigned short* bG0 = B + (unsigned long)(n0 + w * 32 + (l >> 2)) * K + ((l & 3) << 3);
    const unsigned short* bG1 = bG0 + 16ul * K;

    const int nIter = K >> 5;

    auto stage = [&](int it, int buf) {
        const int k0 = it << 5;
        unsigned short* as = As + buf * 4096 + w * 1024;
        unsigned short* bs = Bs + buf * 4096 + w * 1024;
        gload16(aG0 + k0, as);
        gload16(aG1 + k0, as + 512);
        gload16(bG0 + k0, bs);
        gload16(bG1 + k0, bs + 512);
    };

    f32x4 acc[4][4];
#pragma unroll
    for (int mi = 0; mi < 4; ++mi)
#pragma unroll
        for (int ni = 0; ni < 4; ++ni)
            acc[mi][ni] = (f32x4){0.f, 0.f, 0.f, 0.f};

    stage(0, 0);
    stage(1, 1);

    int cb = 0;  // compute buffer
    int sb = 2;  // stage-ahead buffer
    for (int it = 0; it < nIter; ++it) {
        // ensure stage(it) landed; allow stage(it+1) (4 loads) to stay in flight
        if (it + 1 < nIter) __builtin_amdgcn_s_waitcnt(WAIT_VM4);
        else                __builtin_amdgcn_s_waitcnt(WAIT_VM0);
        __builtin_amdgcn_s_barrier();
        if (it + 2 < nIter) stage(it + 2, sb);

        const unsigned short* as = As + cb * 4096;
        const unsigned short* bs = Bs + cb * 4096;
        bf16x8 af[4], bfr[4];
#pragma unroll
        for (int mi = 0; mi < 4; ++mi)
            af[mi] = *(const bf16x8*)&as[(wm * 64 + mi * 16 + t) * 32 + quad * 8];
#pragma unroll
        for (int ni = 0; ni < 4; ++ni)
            bfr[ni] = *(const bf16x8*)&bs[(wn * 64 + ni * 16 + t) * 32 + quad * 8];
#pragma unroll
        for (int mi = 0; mi < 4; ++mi)
#pragma unroll
            for (int ni = 0; ni < 4; ++ni)
                acc[mi][ni] = __builtin_amdgcn_mfma_f32_16x16x32_bf16(
                    af[mi], bfr[ni], acc[mi][ni], 0, 0, 0);

        cb = (cb == 2) ? 0 : cb + 1;
        sb = (sb == 2) ? 0 : sb + 1;
    }

    // epilogue: C/D layout col=lane&15, row=quad*4+reg
#pragma unroll
    for (int mi = 0; mi < 4; ++mi) {
#pragma unroll
        for (int ni = 0; ni < 4; ++ni) {
            const int col = n0 + wn * 64 + ni * 16 + t;
            float bsv = hasBias ? b2f(bias[col]) : 0.f;
            const int row0 = m0 + wm * 64 + mi * 16 + quad * 4;
#pragma unroll
            for (int r = 0; r < 4; ++r) {
                float v = acc[mi][ni][r] + bsv;
                const unsigned long idx = trans
                    ? (unsigned long)col * ldc + (row0 + r)
                    : (unsigned long)(row0 + r) * ldc + col;
                if (outF32) ((float*)Cout)[idx] = v;
                else        ((unsigned short*)Cout)[idx] = f2b(v);
            }
        }
    }
}

// fused QKV projection: grid (16, 36); y<28 -> Q, y<32 -> K, else -> V^T
__global__ __launch_bounds__(256) void gemm_qkv(
    const unsigned short* __restrict__ Xb,
    const unsigned short* __restrict__ Wqb, const unsigned short* __restrict__ Wkb,
    const unsigned short* __restrict__ Wvb,
    const unsigned short* __restrict__ bqb, const unsigned short* __restrict__ bkb,
    const unsigned short* __restrict__ bvb,
    unsigned short* __restrict__ Qb, unsigned short* __restrict__ Kb,
    unsigned short* __restrict__ VT)
{
    __shared__ unsigned short As[3 * 128 * 32];
    __shared__ unsigned short Bs[3 * 128 * 32];
    const int y = blockIdx.y;
    const int m0 = blockIdx.x * 128;
    if (y < 28)
        gemm_pipe(Xb, Wqb, bqb, Qb, HID, HID, m0, y * 128, false, true, false, As, Bs);
    else if (y < 32)
        gemm_pipe(Xb, Wkb, bkb, Kb, HID, NKV * HD, m0, (y - 28) * 128, false, true, false, As, Bs);
    else
        gemm_pipe(Xb, Wvb, bvb, VT, HID, S_LEN, m0, (y - 32) * 128, true, true, false, As, Bs);
}

// output projection: out = Ao * Wo^T, dtype per flag
__global__ __launch_bounds__(256) void gemm_out(
    const unsigned short* __restrict__ Ao, const unsigned short* __restrict__ Wob,
    void* __restrict__ out, const int* __restrict__ flag)
{
    __shared__ unsigned short As[3 * 128 * 32];
    __shared__ unsigned short Bs[3 * 128 * 32];
    gemm_pipe(Ao, Wob, nullptr, out, HID, HID, blockIdx.x * 128, blockIdx.y * 128,
              false, false, flag[0] != 0, As, Bs);
}

// ---------- RoPE in-place on Q [S,3584] and K [S,512] ----------
__global__ __launch_bounds__(64) void rope_kernel(
    unsigned short* __restrict__ Q, unsigned short* __restrict__ Kb,
    const int* __restrict__ pos)
{
    const int s = blockIdx.x;
    const int d = threadIdx.x;  // 0..63 dim pairs
    const bool p64 = (pos[1] == 0 && pos[2] == 1);
    const int pv = p64 ? pos[2 * s] : pos[s];
    const float inv = exp2f(-((float)(2 * d) / 128.0f) * 13.287712379549449f);
    const float f  = (float)pv * inv;
    const float c  = cosf(f);
    const float sn = sinf(f);

    for (int h = 0; h < NH; ++h) {
        unsigned long base = (unsigned long)s * HID + h * HD;
        float x1 = b2f(Q[base + d]);
        float x2 = b2f(Q[base + d + 64]);
        Q[base + d]      = f2b(x1 * c - x2 * sn);
        Q[base + d + 64] = f2b(x2 * c + x1 * sn);
    }
    for (int h = 0; h < NKV; ++h) {
        unsigned long base = (unsigned long)s * (NKV * HD) + h * HD;
        float x1 = b2f(Kb[base + d]);
        float x2 = b2f(Kb[base + d + 64]);
        Kb[base + d]      = f2b(x1 * c - x2 * sn);
        Kb[base + d + 64] = f2b(x2 * c + x1 * sn);
    }
}

// ---------- causal GQA flash attention (swizzled LDS, dbuf, LPT) ----------
#define PSTR 72

__global__ __launch_bounds__(256) void attn_kernel(
    const unsigned short* __restrict__ Q,
    const unsigned short* __restrict__ Kb,
    const unsigned short* __restrict__ VT,
    unsigned short* __restrict__ Ao)
{
    __shared__ unsigned short Ks[2][64 * 128];
    __shared__ unsigned short VTs[2][128 * 64];
    __shared__ unsigned short Ps[4 * 16 * PSTR];

    const int h   = blockIdx.x;
    const int qt  = 31 - (int)blockIdx.y;  // LPT
    const int q0  = qt * 64;
    const int hkv = h / GQA;
    const int tid = threadIdx.x;
    const int w    = tid >> 6;
    const int l    = tid & 63;
    const int quad = l >> 4;
    const int t    = l & 15;
    const int t7   = t & 7;

    bf16x8 qf[4];
    {
        const unsigned short* qrow =
            Q + (unsigned long)(q0 + w * 16 + t) * HID + h * HD + quad * 8;
#pragma unroll
        for (int ks = 0; ks < 4; ++ks)
            qf[ks] = *(const bf16x8*)(qrow + ks * 32);
    }

    f32x4 o[8];
#pragma unroll
    for (int n = 0; n < 8; ++n) o[n] = (f32x4){0.f, 0.f, 0.f, 0.f};
    float mrow[4], lrow[4];
#pragma unroll
    for (int r = 0; r < 4; ++r) { mrow[r] = -1e30f; lrow[r] = 0.f; }

    const int r4  = l >> 4;
    const int c16 = l & 15;
    const int r8  = l >> 3;
    const int c8  = l & 7;
    const unsigned short* kRow =
        Kb + (unsigned long)(w * 16 + r4) * (NKV * HD) + hkv * HD;
    const unsigned short* vRow =
        VT + (unsigned long)(hkv * HD + w * 32 + r8) * S_LEN + ((c8 ^ r8) * 8);

    const int ntiles = qt + 1;

    auto stage = [&](int it, int buf) {
        const int kv0 = it * 64;
#pragma unroll
        for (int i = 0; i < 4; ++i) {
            const int xi = (i * 4 + r4) & 7;
            gload16(kRow + (unsigned long)(kv0 + i * 4) * (NKV * HD) + ((c16 ^ xi) * 8),
                    &Ks[buf][w * 2048 + i * 512]);
            gload16(vRow + (unsigned long)(i * 8) * S_LEN + kv0,
                    &VTs[buf][w * 2048 + i * 512]);
        }
    };

    stage(0, 0);

    for (int it = 0; it < ntiles; ++it) {
        const int cur = it & 1;
        const int kv0 = it * 64;

        __syncthreads();
        if (it + 1 < ntiles) stage(it + 1, cur ^ 1);

        f32x4 sacc[4];
#pragma unroll
        for (int c = 0; c < 4; ++c) sacc[c] = (f32x4){0.f, 0.f, 0.f, 0.f};
#pragma unroll
        for (int c = 0; c < 4; ++c)
#pragma unroll
            for (int ks = 0; ks < 4; ++ks) {
                bf16x8 kf = *(const bf16x8*)
                    &Ks[cur][(c * 16 + t) * 128 + (((ks * 4 + quad) ^ t7) * 8)];
                sacc[c] = __builtin_amdgcn_mfma_f32_16x16x32_bf16(qf[ks], kf, sacc[c], 0, 0, 0);
            }

        const bool last = (it == ntiles - 1);
        float s[4][4];
#pragma unroll
        for (int c = 0; c < 4; ++c)
#pragma unroll
            for (int r = 0; r < 4; ++r) {
                float v = sacc[c][r] * SM_SCALE;
                if (last) {
                    int colg = kv0 + c * 16 + t;
                    int rowg = q0 + w * 16 + quad * 4 + r;
                    if (colg > rowg) v = -1e30f;
                }
                s[c][r] = v;
            }

        float mnew[4];
#pragma unroll
        for (int r = 0; r < 4; ++r)
            mnew[r] = fmaxf(fmaxf(s[0][r], s[1][r]), fmaxf(s[2][r], s[3][r]));
#pragma unroll
        for (int off = 1; off < 16; off <<= 1)
#pragma unroll
            for (int r = 0; r < 4; ++r)
                mnew[r] = fmaxf(mnew[r], __shfl_xor(mnew[r], off));
#pragma unroll
        for (int r = 0; r < 4; ++r) mnew[r] = fmaxf(mnew[r], mrow[r]);

        float alpha[4];
#pragma unroll
        for (int r = 0; r < 4; ++r)
            alpha[r] = exp2f((mrow[r] - mnew[r]) * LOG2E);

        float p[4][4];
#pragma unroll
        for (int c = 0; c < 4; ++c)
#pragma unroll
            for (int r = 0; r < 4; ++r)
                p[c][r] = exp2f((s[c][r] - mnew[r]) * LOG2E);

        float psum[4];
#pragma unroll
        for (int r = 0; r < 4; ++r)
            psum[r] = (p[0][r] + p[1][r]) + (p[2][r] + p[3][r]);
#pragma unroll
        for (int off = 1; off < 16; off <<= 1)
#pragma unroll
            for (int r = 0; r < 4; ++r)
                psum[r] += __shfl_xor(psum[r], off);

#pragma unroll
        for (int r = 0; r < 4; ++r) {
            lrow[r] = lrow[r] * alpha[r] + psum[r];
            mrow[r] = mnew[r];
        }
#pragma unroll
        for (int n = 0; n < 8; ++n)
#pragma unroll
            for (int r = 0; r < 4; ++r)
                o[n][r] *= alpha[r];

#pragma unroll
        for (int c = 0; c < 4; ++c)
#pragma unroll
            for (int r = 0; r < 4; ++r)
                Ps[w * (16 * PSTR) + (quad * 4 + r) * PSTR + c * 16 + t] = f2b(p[c][r]);

        bf16x8 pf0, pf1;
        __builtin_memcpy(&pf0, &Ps[w * (16 * PSTR) + t * PSTR + quad * 8], 16);
        __builtin_memcpy(&pf1, &Ps[w * (16 * PSTR) + t * PSTR + 32 + quad * 8], 16);

#pragma unroll
        for (int n = 0; n < 8; ++n) {
            bf16x8 v0 = *(const bf16x8*)
                &VTs[cur][(n * 16 + t) * 64 + ((quad ^ t7) * 8)];
            bf16x8 v1 = *(const bf16x8*)
                &VTs[cur][(n * 16 + t) * 64 + (((4 + quad) ^ t7) * 8)];
            o[n] = __builtin_amdgcn_mfma_f32_16x16x32_bf16(pf0, v0, o[n], 0, 0, 0);
            o[n] = __builtin_amdgcn_mfma_f32_16x16x32_bf16(pf1, v1, o[n], 0, 0, 0);
        }
    }

#pragma unroll
    for (int n = 0; n < 8; ++n) {
#pragma unroll
        for (int r = 0; r < 4; ++r) {
            float v = o[n][r] / lrow[r];
            unsigned long row = q0 + w * 16 + quad * 4 + r;
            Ao[row * HID + h * HD + n * 16 + t] = f2b(v);
        }
    }
}

extern "C" void kernel_launch(void* const* d_in, const int* in_sizes, int n_in,
                              void* d_out, int out_size, void* d_ws, size_t ws_size,
                              hipStream_t stream) {
    const void* X  = d_in[0];
    const int* pos = (const int*)d_in[1];
    const void* Wq = d_in[2];
    const void* bq = d_in[3];
    const void* Wk = d_in[4];
    const void* bk = d_in[5];
    const void* Wv = d_in[6];
    const void* bv = d_in[7];
    const void* Wo = d_in[8];

    char* ws = (char*)d_ws;
    int*            flag = (int*)(ws + 0);
    unsigned short* dst  = (unsigned short*)(ws + 16);
    unsigned short* Xb  = dst;
    unsigned short* Wqb = dst + SEG_B1;
    unsigned short* Wkb = dst + SEG_B2;
    unsigned short* Wvb = dst + SEG_B3;
    unsigned short* Wob = dst + SEG_B4;
    unsigned short* bqb = dst + SEG_B5;
    unsigned short* bkb = dst + SEG_B6;
    unsigned short* bvb = dst + SEG_B7;
    unsigned short* Qb  = (unsigned short*)(ws + 73409552);   // [2048][3584]
    unsigned short* Kb  = (unsigned short*)(ws + 88089616);   // [2048][512]
    unsigned short* VT  = (unsigned short*)(ws + 90186768);   // [512][2048]
    unsigned short* Ao  = (unsigned short*)(ws + 92283920);   // [2048][3584]
    // total ws use: 106,963,984 bytes

    dim3 blk(256);
    detect_kernel<<<1, blk, 0, stream>>>((const unsigned short*)X, flag);
    convert_all<<<dim3((unsigned)((SEG_B8 + 2047) / 2048)), blk, 0, stream>>>(
        X, Wq, Wk, Wv, Wo, bq, bk, bv, dst, flag);

    gemm_qkv<<<dim3(16, 36), blk, 0, stream>>>(Xb, Wqb, Wkb, Wvb, bqb, bkb, bvb,
                                               Qb, Kb, VT);
    rope_kernel<<<dim3(S_LEN), dim3(64), 0, stream>>>(Qb, Kb, pos);
    attn_kernel<<<dim3(NH, 32), blk, 0, stream>>>(Qb, Kb, VT, Ao);
    gemm_out<<<dim3(16, 28), blk, 0, stream>>>(Ao, Wob, d_out, flag);
}

// Round 7
// 497.821 us; speedup vs baseline: 1.1843x; 1.1843x over previous
//
#include <hip/hip_runtime.h>
#include <hip/hip_bf16.h>

// Qwen2 attention layer: S=2048, HIDDEN=3584, 28 Q heads, 4 KV heads, D=128.
// fp32 inputs auto-detected -> bf16 pipeline (MFMA), fp32 output.
// R7: revert R6 raw-barrier pipe (regressed, per m131/m141 precedent).
// GEMMs: split-K=2 + BK=64 (half the barrier drains per K, 32KB LDS keeps
// occupancy) with XOR-swizzled LDS (row stride 128B needs it). reduce_qkv
// fused with RoPE (one pass, one dispatch fewer).

#define S_LEN 2048
#define HID   3584
#define NH    28
#define NKV   4
#define HD    128
#define GQA   7

using bf16x8 = __attribute__((ext_vector_type(8))) __bf16;
using f32x4  = __attribute__((ext_vector_type(4))) float;

#define LOG2E 1.4426950408889634f
#define SM_SCALE 0.08838834764831845f  // 1/sqrt(128)
#define LOG2_10K 13.287712379549449f

__device__ __forceinline__ float b2f(unsigned short u) {
    unsigned int x = ((unsigned int)u) << 16;
    float f;
    __builtin_memcpy(&f, &x, 4);
    return f;
}

__device__ __forceinline__ unsigned short f2b(float f) {
    unsigned int i;
    __builtin_memcpy(&i, &f, 4);
    i += 0x7FFFu + ((i >> 16) & 1u);  // RNE
    return (unsigned short)(i >> 16);
}

__device__ __forceinline__ void gload16(const void* g, void* l) {
    __builtin_amdgcn_global_load_lds(
        (__attribute__((address_space(1))) void*)(g),
        (__attribute__((address_space(3))) void*)(l), 16, 0, 0);
}

// ---------- dtype detection ----------
__global__ __launch_bounds__(256) void detect_kernel(
    const unsigned short* __restrict__ X, int* __restrict__ flag)
{
    __shared__ int sflag;
    if (threadIdx.x == 0) sflag = 0;
    __syncthreads();
    bool insane = false;
    for (int i = threadIdx.x; i < 8192; i += 256) {
        unsigned int e = (X[i] >> 7) & 0xFF;
        if (e >= 0xE0) insane = true;
    }
    if (insane) sflag = 1;  // benign race
    __syncthreads();
    if (threadIdx.x == 0) flag[0] = sflag;
}

// ---------- fused convert: all 8 tensors -> one contiguous bf16 region ----------
#define SEG_B1 7340032L
#define SEG_B2 20185088L
#define SEG_B3 22020096L
#define SEG_B4 23855104L
#define SEG_B5 36700160L
#define SEG_B6 36703744L
#define SEG_B7 36704256L
#define SEG_B8 36704768L

__global__ __launch_bounds__(256) void convert_all(
    const void* __restrict__ s0, const void* __restrict__ s1,
    const void* __restrict__ s2, const void* __restrict__ s3,
    const void* __restrict__ s4, const void* __restrict__ s5,
    const void* __restrict__ s6, const void* __restrict__ s7,
    unsigned short* __restrict__ dst, const int* __restrict__ flag)
{
    const long i0 = ((long)blockIdx.x * 256 + threadIdx.x) * 8;
    if (i0 >= SEG_B8) return;
    const void* src;
    long off;
    if      (i0 < SEG_B1) { src = s0; off = i0; }
    else if (i0 < SEG_B2) { src = s1; off = i0 - SEG_B1; }
    else if (i0 < SEG_B3) { src = s2; off = i0 - SEG_B2; }
    else if (i0 < SEG_B4) { src = s3; off = i0 - SEG_B3; }
    else if (i0 < SEG_B5) { src = s4; off = i0 - SEG_B4; }
    else if (i0 < SEG_B6) { src = s5; off = i0 - SEG_B5; }
    else if (i0 < SEG_B7) { src = s6; off = i0 - SEG_B6; }
    else                  { src = s7; off = i0 - SEG_B7; }
    if (flag[0] != 0) {
        const float* s = (const float*)src + off;
        unsigned short o[8];
#pragma unroll
        for (int j = 0; j < 8; ++j) o[j] = f2b(s[j]);
        *(uint4*)(dst + i0) = *(const uint4*)o;
    } else {
        *(uint4*)(dst + i0) = *(const uint4*)((const unsigned short*)src + off);
    }
}

// ---------- split-K GEMM partial core, BK=64, swizzled LDS ----------
// 128x128 tile, 256 threads, single-buffered 32 KB LDS, m97 2-barrier loop.
// LDS layout: [row][chunk] with physical chunk = logical ^ (row&7); staging
// permutes the global SOURCE column per lane (dest stays lane-contiguous).
__device__ __forceinline__ void gemm_part64(
    const unsigned short* __restrict__ A,
    const unsigned short* __restrict__ B,
    float* __restrict__ P,
    int Kstride, int Kspan, int m0, int n0loc, int ldp, int colbase,
    unsigned short* As, unsigned short* Bs)   // each 128*64 shorts
{
    const int tid  = threadIdx.x;
    const int w    = tid >> 6;
    const int l    = tid & 63;
    const int quad = l >> 4;
    const int t    = l & 15;
    const int t7   = t & 7;
    const int wm   = w >> 1;
    const int wn   = w & 1;

    const int lr = l >> 3;                 // row-in-issue (0..7)
    const int sc = (l & 7) ^ lr;           // swizzled source chunk
    const unsigned short* aG = A + (unsigned long)(m0 + w * 32 + lr) * Kstride + sc * 8;
    const unsigned short* bG = B + (unsigned long)(n0loc + w * 32 + lr) * Kstride + sc * 8;
    unsigned short* asD = As + w * 2048;
    unsigned short* bsD = Bs + w * 2048;

    f32x4 acc[4][4];
#pragma unroll
    for (int mi = 0; mi < 4; ++mi)
#pragma unroll
        for (int ni = 0; ni < 4; ++ni)
            acc[mi][ni] = (f32x4){0.f, 0.f, 0.f, 0.f};

    for (int k0 = 0; k0 < Kspan; k0 += 64) {
#pragma unroll
        for (int i = 0; i < 4; ++i) {
            gload16(aG + k0 + (unsigned long)(i * 8) * Kstride, asD + i * 512);
            gload16(bG + k0 + (unsigned long)(i * 8) * Kstride, bsD + i * 512);
        }
        __syncthreads();

#pragma unroll
        for (int ks = 0; ks < 2; ++ks) {
            bf16x8 af[4], bfr[4];
#pragma unroll
            for (int mi = 0; mi < 4; ++mi)
                af[mi] = *(const bf16x8*)
                    &As[(wm * 64 + mi * 16 + t) * 64 + (((ks * 4 + quad) ^ t7) * 8)];
#pragma unroll
            for (int ni = 0; ni < 4; ++ni)
                bfr[ni] = *(const bf16x8*)
                    &Bs[(wn * 64 + ni * 16 + t) * 64 + (((ks * 4 + quad) ^ t7) * 8)];
#pragma unroll
            for (int mi = 0; mi < 4; ++mi)
#pragma unroll
                for (int ni = 0; ni < 4; ++ni)
                    acc[mi][ni] = __builtin_amdgcn_mfma_f32_16x16x32_bf16(
                        af[mi], bfr[ni], acc[mi][ni], 0, 0, 0);
        }
        __syncthreads();
    }

    // fp32 partial write; C/D layout col=lane&15, row=quad*4+reg
#pragma unroll
    for (int mi = 0; mi < 4; ++mi) {
#pragma unroll
        for (int ni = 0; ni < 4; ++ni) {
            const int col = colbase + wn * 64 + ni * 16 + t;
            const int row0 = m0 + wm * 64 + mi * 16 + quad * 4;
#pragma unroll
            for (int r = 0; r < 4; ++r)
                P[(unsigned long)(row0 + r) * ldp + col] = acc[mi][ni][r];
        }
    }
}

// grid (16, 36, 2): y<28 Q cols, y<32 K cols, else V cols; z = K-half.
__global__ __launch_bounds__(256) void gemm_qkv_split(
    const unsigned short* __restrict__ Xb,
    const unsigned short* __restrict__ Wqb, const unsigned short* __restrict__ Wkb,
    const unsigned short* __restrict__ Wvb,
    float* __restrict__ P)
{
    __shared__ unsigned short As[128 * 64];
    __shared__ unsigned short Bs[128 * 64];
    const int y  = blockIdx.y;
    const int m0 = blockIdx.x * 128;
    const int klo = blockIdx.z * (HID / 2);
    float* Pz = P + (unsigned long)blockIdx.z * S_LEN * 4608;
    if (y < 28)
        gemm_part64(Xb + klo, Wqb + klo, Pz, HID, HID / 2, m0, y * 128, 4608, y * 128, As, Bs);
    else if (y < 32)
        gemm_part64(Xb + klo, Wkb + klo, Pz, HID, HID / 2, m0, (y - 28) * 128, 4608,
                    3584 + (y - 28) * 128, As, Bs);
    else
        gemm_part64(Xb + klo, Wvb + klo, Pz, HID, HID / 2, m0, (y - 32) * 128, 4608,
                    4096 + (y - 32) * 128, As, Bs);
}

// grid (16, 28, 2)
__global__ __launch_bounds__(256) void gemm_out_split(
    const unsigned short* __restrict__ Ao, const unsigned short* __restrict__ Wob,
    float* __restrict__ P)
{
    __shared__ unsigned short As[128 * 64];
    __shared__ unsigned short Bs[128 * 64];
    const int klo = blockIdx.z * (HID / 2);
    float* Pz = P + (unsigned long)blockIdx.z * S_LEN * HID;
    gemm_part64(Ao + klo, Wob + klo, Pz, HID, HID / 2, blockIdx.x * 128,
                blockIdx.y * 128, HID, blockIdx.y * 128, As, Bs);
}

// ---------- fused reduce + bias + RoPE ----------
// g < 524288: Q/K rope region. thread -> (m, h32, chunk c of 8 dim-pairs);
// reads both P halves at n and n+64, adds bias, applies rope, writes bf16.
// else: V region -> VT transpose store.
__global__ __launch_bounds__(256) void reduce_rope(
    const float* __restrict__ P,
    const unsigned short* __restrict__ bq, const unsigned short* __restrict__ bk,
    const unsigned short* __restrict__ bv,
    unsigned short* __restrict__ Qb, unsigned short* __restrict__ Kb,
    unsigned short* __restrict__ VT, const int* __restrict__ pos)
{
    const long g = (long)blockIdx.x * 256 + threadIdx.x;
    const bool p64 = (pos[1] == 0 && pos[2] == 1);
    if (g < 524288) {
        const int c   = (int)(g & 7);
        const int h32 = (int)((g >> 3) & 31);
        const int m   = (int)(g >> 8);
        const int d0  = c * 8;
        const int pv  = p64 ? pos[2 * m] : pos[m];
        const bool isQ = (h32 < 28);
        const int nlo = isQ ? h32 * 128 + d0 : 3584 + (h32 - 28) * 128 + d0;
        const float* p0 = P + (long)m * 4608 + nlo;
        const float* p1 = p0 + (long)S_LEN * 4608;
        const unsigned short* bias = isQ ? bq + h32 * 128 + d0
                                         : bk + (h32 - 28) * 128 + d0;
        float xlo[8], xhi[8];
#pragma unroll
        for (int j = 0; j < 8; ++j) {
            xlo[j] = p0[j] + p1[j] + b2f(bias[j]);
            xhi[j] = p0[j + 64] + p1[j + 64] + b2f(bias[j + 64]);
        }
        unsigned short olo[8], ohi[8];
#pragma unroll
        for (int j = 0; j < 8; ++j) {
            const float inv = exp2f(-((float)(2 * (d0 + j)) / 128.0f) * LOG2_10K);
            const float a = (float)pv * inv;
            const float cs = cosf(a), sn = sinf(a);
            olo[j] = f2b(xlo[j] * cs - xhi[j] * sn);
            ohi[j] = f2b(xhi[j] * cs + xlo[j] * sn);
        }
        unsigned short* dst = isQ ? Qb + (long)m * HID + h32 * 128 + d0
                                  : Kb + (long)m * (NKV * HD) + (h32 - 28) * 128 + d0;
        *(uint4*)dst        = *(const uint4*)olo;
        *(uint4*)(dst + 64) = *(const uint4*)ohi;
    } else {
        const long gv = g - 524288;  // < 131072
        const int c = (int)(gv & 63);
        const int m = (int)(gv >> 6);
        const int nv = c * 8;
        const float* p0 = P + (long)m * 4608 + 4096 + nv;
        const float* p1 = p0 + (long)S_LEN * 4608;
#pragma unroll
        for (int j = 0; j < 8; ++j)
            VT[(long)(nv + j) * S_LEN + m] = f2b(p0[j] + p1[j] + b2f(bv[nv + j]));
    }
}

__global__ __launch_bounds__(256) void reduce_out(
    const float* __restrict__ P, void* __restrict__ out, const int* __restrict__ flag)
{
    const long i = ((long)blockIdx.x * 256 + threadIdx.x) * 8;
    if (i >= (long)S_LEN * HID) return;
    const float* p0 = P + i;
    const float* p1 = P + (long)S_LEN * HID + i;
    float v[8];
#pragma unroll
    for (int j = 0; j < 8; ++j) v[j] = p0[j] + p1[j];
    if (flag[0] != 0) {
        float* o = (float*)out + i;
#pragma unroll
        for (int j = 0; j < 8; ++j) o[j] = v[j];
    } else {
        unsigned short o[8];
#pragma unroll
        for (int j = 0; j < 8; ++j) o[j] = f2b(v[j]);
        *(uint4*)((unsigned short*)out + i) = *(const uint4*)o;
    }
}

// ---------- fallback (ws too small): BK=32 full-K GEMM + separate rope ----------
__device__ __forceinline__ void gemm_core(
    const unsigned short* __restrict__ A,
    const unsigned short* __restrict__ B,
    const unsigned short* __restrict__ bias,
    void* __restrict__ Cout,
    int K, int ldc, int m0, int n0,
    bool trans, bool hasBias, bool outF32,
    unsigned short* As, unsigned short* Bs)
{
    const int tid  = threadIdx.x;
    const int w    = tid >> 6;
    const int l    = tid & 63;
    const int quad = l >> 4;
    const int t    = l & 15;
    const int wm   = w >> 1;
    const int wn   = w & 1;

    const unsigned short* aG0 = A + (unsigned long)(m0 + w * 32 + (l >> 2)) * K + ((l & 3) << 3);
    const unsigned short* aG1 = aG0 + 16ul * K;
    const unsigned short* bG0 = B + (unsigned long)(n0 + w * 32 + (l >> 2)) * K + ((l & 3) << 3);
    const unsigned short* bG1 = bG0 + 16ul * K;

    f32x4 acc[4][4];
#pragma unroll
    for (int mi = 0; mi < 4; ++mi)
#pragma unroll
        for (int ni = 0; ni < 4; ++ni)
            acc[mi][ni] = (f32x4){0.f, 0.f, 0.f, 0.f};

    for (int k0 = 0; k0 < K; k0 += 32) {
        gload16(aG0 + k0, &As[w * 1024]);
        gload16(aG1 + k0, &As[w * 1024 + 512]);
        gload16(bG0 + k0, &Bs[w * 1024]);
        gload16(bG1 + k0, &Bs[w * 1024 + 512]);
        __syncthreads();

        bf16x8 af[4], bfr[4];
#pragma unroll
        for (int mi = 0; mi < 4; ++mi)
            af[mi] = *(const bf16x8*)&As[(wm * 64 + mi * 16 + t) * 32 + quad * 8];
#pragma unroll
        for (int ni = 0; ni < 4; ++ni)
            bfr[ni] = *(const bf16x8*)&Bs[(wn * 64 + ni * 16 + t) * 32 + quad * 8];
#pragma unroll
        for (int mi = 0; mi < 4; ++mi)
#pragma unroll
            for (int ni = 0; ni < 4; ++ni)
                acc[mi][ni] = __builtin_amdgcn_mfma_f32_16x16x32_bf16(
                    af[mi], bfr[ni], acc[mi][ni], 0, 0, 0);
        __syncthreads();
    }

#pragma unroll
    for (int mi = 0; mi < 4; ++mi) {
#pragma unroll
        for (int ni = 0; ni < 4; ++ni) {
            const int col = n0 + wn * 64 + ni * 16 + t;
            float bsv = hasBias ? b2f(bias[col]) : 0.f;
            const int row0 = m0 + wm * 64 + mi * 16 + quad * 4;
#pragma unroll
            for (int r = 0; r < 4; ++r) {
                float v = acc[mi][ni][r] + bsv;
                const unsigned long idx = trans
                    ? (unsigned long)col * ldc + (row0 + r)
                    : (unsigned long)(row0 + r) * ldc + col;
                if (outF32) ((float*)Cout)[idx] = v;
                else        ((unsigned short*)Cout)[idx] = f2b(v);
            }
        }
    }
}

__global__ __launch_bounds__(256) void gemm_qkv(
    const unsigned short* __restrict__ Xb,
    const unsigned short* __restrict__ Wqb, const unsigned short* __restrict__ Wkb,
    const unsigned short* __restrict__ Wvb,
    const unsigned short* __restrict__ bqb, const unsigned short* __restrict__ bkb,
    const unsigned short* __restrict__ bvb,
    unsigned short* __restrict__ Qb, unsigned short* __restrict__ Kb,
    unsigned short* __restrict__ VT)
{
    __shared__ unsigned short As[128 * 32];
    __shared__ unsigned short Bs[128 * 32];
    const int y = blockIdx.y;
    const int m0 = blockIdx.x * 128;
    if (y < 28)
        gemm_core(Xb, Wqb, bqb, Qb, HID, HID, m0, y * 128, false, true, false, As, Bs);
    else if (y < 32)
        gemm_core(Xb, Wkb, bkb, Kb, HID, NKV * HD, m0, (y - 28) * 128, false, true, false, As, Bs);
    else
        gemm_core(Xb, Wvb, bvb, VT, HID, S_LEN, m0, (y - 32) * 128, true, true, false, As, Bs);
}

__global__ __launch_bounds__(256) void gemm_out(
    const unsigned short* __restrict__ Ao, const unsigned short* __restrict__ Wob,
    void* __restrict__ out, const int* __restrict__ flag)
{
    __shared__ unsigned short As[128 * 32];
    __shared__ unsigned short Bs[128 * 32];
    gemm_core(Ao, Wob, nullptr, out, HID, HID, blockIdx.x * 128, blockIdx.y * 128,
              false, false, flag[0] != 0, As, Bs);
}

__global__ __launch_bounds__(64) void rope_kernel(
    unsigned short* __restrict__ Q, unsigned short* __restrict__ Kb,
    const int* __restrict__ pos)
{
    const int s = blockIdx.x;
    const int d = threadIdx.x;
    const bool p64 = (pos[1] == 0 && pos[2] == 1);
    const int pv = p64 ? pos[2 * s] : pos[s];
    const float inv = exp2f(-((float)(2 * d) / 128.0f) * LOG2_10K);
    const float f  = (float)pv * inv;
    const float c  = cosf(f);
    const float sn = sinf(f);

    for (int h = 0; h < NH; ++h) {
        unsigned long base = (unsigned long)s * HID + h * HD;
        float x1 = b2f(Q[base + d]);
        float x2 = b2f(Q[base + d + 64]);
        Q[base + d]      = f2b(x1 * c - x2 * sn);
        Q[base + d + 64] = f2b(x2 * c + x1 * sn);
    }
    for (int h = 0; h < NKV; ++h) {
        unsigned long base = (unsigned long)s * (NKV * HD) + h * HD;
        float x1 = b2f(Kb[base + d]);
        float x2 = b2f(Kb[base + d + 64]);
        Kb[base + d]      = f2b(x1 * c - x2 * sn);
        Kb[base + d + 64] = f2b(x2 * c + x1 * sn);
    }
}

// ---------- causal GQA flash attention (swizzled LDS, dbuf, LPT) ----------
#define PSTR 72

__global__ __launch_bounds__(256) void attn_kernel(
    const unsigned short* __restrict__ Q,
    const unsigned short* __restrict__ Kb,
    const unsigned short* __restrict__ VT,
    unsigned short* __restrict__ Ao)
{
    __shared__ unsigned short Ks[2][64 * 128];
    __shared__ unsigned short VTs[2][128 * 64];
    __shared__ unsigned short Ps[4 * 16 * PSTR];

    const int h   = blockIdx.x;
    const int qt  = 31 - (int)blockIdx.y;  // LPT
    const int q0  = qt * 64;
    const int hkv = h / GQA;
    const int tid = threadIdx.x;
    const int w    = tid >> 6;
    const int l    = tid & 63;
    const int quad = l >> 4;
    const int t    = l & 15;
    const int t7   = t & 7;

    bf16x8 qf[4];
    {
        const unsigned short* qrow =
            Q + (unsigned long)(q0 + w * 16 + t) * HID + h * HD + quad * 8;
#pragma unroll
        for (int ks = 0; ks < 4; ++ks)
            qf[ks] = *(const bf16x8*)(qrow + ks * 32);
    }

    f32x4 o[8];
#pragma unroll
    for (int n = 0; n < 8; ++n) o[n] = (f32x4){0.f, 0.f, 0.f, 0.f};
    float mrow[4], lrow[4];
#pragma unroll
    for (int r = 0; r < 4; ++r) { mrow[r] = -1e30f; lrow[r] = 0.f; }

    const int r4  = l >> 4;
    const int c16 = l & 15;
    const int r8  = l >> 3;
    const int c8  = l & 7;
    const unsigned short* kRow =
        Kb + (unsigned long)(w * 16 + r4) * (NKV * HD) + hkv * HD;
    const unsigned short* vRow =
        VT + (unsigned long)(hkv * HD + w * 32 + r8) * S_LEN + ((c8 ^ r8) * 8);

    const int ntiles = qt + 1;

    auto stage = [&](int it, int buf) {
        const int kv0 = it * 64;
#pragma unroll
        for (int i = 0; i < 4; ++i) {
            const int xi = (i * 4 + r4) & 7;
            gload16(kRow + (unsigned long)(kv0 + i * 4) * (NKV * HD) + ((c16 ^ xi) * 8),
                    &Ks[buf][w * 2048 + i * 512]);
            gload16(vRow + (unsigned long)(i * 8) * S_LEN + kv0,
                    &VTs[buf][w * 2048 + i * 512]);
        }
    };

    stage(0, 0);

    for (int it = 0; it < ntiles; ++it) {
        const int cur = it & 1;
        const int kv0 = it * 64;

        __syncthreads();
        if (it + 1 < ntiles) stage(it + 1, cur ^ 1);

        f32x4 sacc[4];
#pragma unroll
        for (int c = 0; c < 4; ++c) sacc[c] = (f32x4){0.f, 0.f, 0.f, 0.f};
#pragma unroll
        for (int c = 0; c < 4; ++c)
#pragma unroll
            for (int ks = 0; ks < 4; ++ks) {
                bf16x8 kf = *(const bf16x8*)
                    &Ks[cur][(c * 16 + t) * 128 + (((ks * 4 + quad) ^ t7) * 8)];
                sacc[c] = __builtin_amdgcn_mfma_f32_16x16x32_bf16(qf[ks], kf, sacc[c], 0, 0, 0);
            }

        const bool last = (it == ntiles - 1);
        float s[4][4];
#pragma unroll
        for (int c = 0; c < 4; ++c)
#pragma unroll
            for (int r = 0; r < 4; ++r) {
                float v = sacc[c][r] * SM_SCALE;
                if (last) {
                    int colg = kv0 + c * 16 + t;
                    int rowg = q0 + w * 16 + quad * 4 + r;
                    if (colg > rowg) v = -1e30f;
                }
                s[c][r] = v;
            }

        float mnew[4];
#pragma unroll
        for (int r = 0; r < 4; ++r)
            mnew[r] = fmaxf(fmaxf(s[0][r], s[1][r]), fmaxf(s[2][r], s[3][r]));
#pragma unroll
        for (int off = 1; off < 16; off <<= 1)
#pragma unroll
            for (int r = 0; r < 4; ++r)
                mnew[r] = fmaxf(mnew[r], __shfl_xor(mnew[r], off));
#pragma unroll
        for (int r = 0; r < 4; ++r) mnew[r] = fmaxf(mnew[r], mrow[r]);

        float alpha[4];
#pragma unroll
        for (int r = 0; r < 4; ++r)
            alpha[r] = exp2f((mrow[r] - mnew[r]) * LOG2E);

        float p[4][4];
#pragma unroll
        for (int c = 0; c < 4; ++c)
#pragma unroll
            for (int r = 0; r < 4; ++r)
                p[c][r] = exp2f((s[c][r] - mnew[r]) * LOG2E);

        float psum[4];
#pragma unroll
        for (int r = 0; r < 4; ++r)
            psum[r] = (p[0][r] + p[1][r]) + (p[2][r] + p[3][r]);
#pragma unroll
        for (int off = 1; off < 16; off <<= 1)
#pragma unroll
            for (int r = 0; r < 4; ++r)
                psum[r] += __shfl_xor(psum[r], off);

#pragma unroll
        for (int r = 0; r < 4; ++r) {
            lrow[r] = lrow[r] * alpha[r] + psum[r];
            mrow[r] = mnew[r];
        }
#pragma unroll
        for (int n = 0; n < 8; ++n)
#pragma unroll
            for (int r = 0; r < 4; ++r)
                o[n][r] *= alpha[r];

#pragma unroll
        for (int c = 0; c < 4; ++c)
#pragma unroll
            for (int r = 0; r < 4; ++r)
                Ps[w * (16 * PSTR) + (quad * 4 + r) * PSTR + c * 16 + t] = f2b(p[c][r]);

        bf16x8 pf0, pf1;
        __builtin_memcpy(&pf0, &Ps[w * (16 * PSTR) + t * PSTR + quad * 8], 16);
        __builtin_memcpy(&pf1, &Ps[w * (16 * PSTR) + t * PSTR + 32 + quad * 8], 16);

#pragma unroll
        for (int n = 0; n < 8; ++n) {
            bf16x8 v0 = *(const bf16x8*)
                &VTs[cur][(n * 16 + t) * 64 + ((quad ^ t7) * 8)];
            bf16x8 v1 = *(const bf16x8*)
                &VTs[cur][(n * 16 + t) * 64 + (((4 + quad) ^ t7) * 8)];
            o[n] = __builtin_amdgcn_mfma_f32_16x16x32_bf16(pf0, v0, o[n], 0, 0, 0);
            o[n] = __builtin_amdgcn_mfma_f32_16x16x32_bf16(pf1, v1, o[n], 0, 0, 0);
        }
    }

#pragma unroll
    for (int n = 0; n < 8; ++n) {
#pragma unroll
        for (int r = 0; r < 4; ++r) {
            float v = o[n][r] / lrow[r];
            unsigned long row = q0 + w * 16 + quad * 4 + r;
            Ao[row * HID + h * HD + n * 16 + t] = f2b(v);
        }
    }
}

extern "C" void kernel_launch(void* const* d_in, const int* in_sizes, int n_in,
                              void* d_out, int out_size, void* d_ws, size_t ws_size,
                              hipStream_t stream) {
    const void* X  = d_in[0];
    const int* pos = (const int*)d_in[1];
    const void* Wq = d_in[2];
    const void* bq = d_in[3];
    const void* Wk = d_in[4];
    const void* bk = d_in[5];
    const void* Wv = d_in[6];
    const void* bv = d_in[7];
    const void* Wo = d_in[8];

    char* ws = (char*)d_ws;
    int*            flag = (int*)(ws + 0);
    unsigned short* dst  = (unsigned short*)(ws + 16);
    unsigned short* Xb  = dst;
    unsigned short* Wqb = dst + SEG_B1;
    unsigned short* Wkb = dst + SEG_B2;
    unsigned short* Wvb = dst + SEG_B3;
    unsigned short* Wob = dst + SEG_B4;
    unsigned short* bqb = dst + SEG_B5;
    unsigned short* bkb = dst + SEG_B6;
    unsigned short* bvb = dst + SEG_B7;
    unsigned short* Qb  = (unsigned short*)(ws + 73409552);   // [2048][3584]
    unsigned short* Kb  = (unsigned short*)(ws + 88089616);   // [2048][512]
    unsigned short* VT  = (unsigned short*)(ws + 90186768);   // [512][2048]
    unsigned short* Ao  = (unsigned short*)(ws + 92283920);   // [2048][3584]
    float*          Pp  = (float*)(ws + 106963984);           // [2][2048][4608] fp32
    const size_t SPLIT_NEED = 106963984ul + 2ul * S_LEN * 4608 * 4;  // ~182.5 MB
    const bool use_split = ws_size >= SPLIT_NEED;

    dim3 blk(256);
    detect_kernel<<<1, blk, 0, stream>>>((const unsigned short*)X, flag);
    convert_all<<<dim3((unsigned)((SEG_B8 + 2047) / 2048)), blk, 0, stream>>>(
        X, Wq, Wk, Wv, Wo, bq, bk, bv, dst, flag);

    if (use_split) {
        gemm_qkv_split<<<dim3(16, 36, 2), blk, 0, stream>>>(Xb, Wqb, Wkb, Wvb, Pp);
        reduce_rope<<<dim3(2560), blk, 0, stream>>>(Pp, bqb, bkb, bvb, Qb, Kb, VT, pos);
    } else {
        gemm_qkv<<<dim3(16, 36), blk, 0, stream>>>(Xb, Wqb, Wkb, Wvb, bqb, bkb, bvb,
                                                   Qb, Kb, VT);
        rope_kernel<<<dim3(S_LEN), dim3(64), 0, stream>>>(Qb, Kb, pos);
    }

    attn_kernel<<<dim3(NH, 32), blk, 0, stream>>>(Qb, Kb, VT, Ao);

    if (use_split) {
        gemm_out_split<<<dim3(16, 28, 2), blk, 0, stream>>>(Ao, Wob, Pp);
        reduce_out<<<dim3(3584), blk, 0, stream>>>(Pp, d_out, flag);
    } else {
        gemm_out<<<dim3(16, 28), blk, 0, stream>>>(Ao, Wob, d_out, flag);
    }
}